// Round 5
// baseline (136.075 us; speedup 1.0000x reference)
//
#include <hip/hip_runtime.h>
#include <hip/hip_bf16.h>
#include <cstdint>

#define N_DIM 4096
#define K_DIM 2048
#define NIT 16   // 32 K-tiles of 64, 2 per iteration

typedef __bf16 bf16x8 __attribute__((ext_vector_type(8)));
typedef float floatx4 __attribute__((ext_vector_type(4)));
typedef unsigned short ushort8 __attribute__((ext_vector_type(8)));
typedef int intx4 __attribute__((ext_vector_type(4)));

__device__ __forceinline__ unsigned short f2bf(float f) {
    unsigned int u = __builtin_bit_cast(unsigned int, f);
    unsigned int r = (u + 0x7fffu + ((u >> 16) & 1u)) >> 16;  // RNE
    return (unsigned short)r;
}

__device__ __forceinline__ void gld_lds16(const void* g, void* l) {
    __builtin_amdgcn_global_load_lds(
        (const __attribute__((address_space(1))) unsigned int*)g,
        (__attribute__((address_space(3))) unsigned int*)l,
        16, 0, 0);
}

__device__ __forceinline__ void stage_half(const unsigned short* src, unsigned short* ldsWave) {
    gld_lds16(src, ldsWave);                       // rows 0-63 of the half
    gld_lds16(src + 64 * K_DIM, ldsWave + 4096);   // rows 64-127 (+8192 B)
}

// ---------------- Kernel 0: cast fp32 -> bf16, compute row squared norms ----
__global__ __launch_bounds__(256)
void prep_kernel(const float* __restrict__ X, unsigned short* __restrict__ Abf,
                 float* __restrict__ sq) {
    const int row = blockIdx.x;
    const int tid = threadIdx.x;
    const float* xr = X + (size_t)row * K_DIM;
    floatx4 a = *(const floatx4*)(xr + tid * 8);
    floatx4 b = *(const floatx4*)(xr + tid * 8 + 4);
    float s = 0.f;
    ushort8 o;
#pragma unroll
    for (int e = 0; e < 4; ++e) {
        s += a[e] * a[e] + b[e] * b[e];
        o[e] = f2bf(a[e]);
        o[4 + e] = f2bf(b[e]);
    }
    *(ushort8*)(Abf + (size_t)row * K_DIM + tid * 8) = o;
#pragma unroll
    for (int off = 32; off; off >>= 1) s += __shfl_down(s, off);
    __shared__ float wsum[4];
    const int wave = tid >> 6, lane = tid & 63;
    if (lane == 0) wsum[wave] = s;
    __syncthreads();
    if (tid == 0) sq[row] = wsum[0] + wsum[1] + wsum[2] + wsum[3];
}

// ---------------- Kernel 1: 256x256 8-phase bf16 MFMA GEMM + dist epilogue --
// 512 thr = 8 waves (2Mx4N). BK=64, 2 K-tiles/iter. ONE-PHASE READ-AHEAD
// register pipeline: phase p MFMAs on frags read at p-1 while issuing reads
// for p+1 into the alternate frag set (afX/afY, bfP/bfQ — compile-time).
// Quadrants: (0,0),(0,1),(1,1),(1,0). Stage slots (gap>=3 to first read):
//   ph1:b1B0 ph2:b1B1 ph3:b1A1 ph4:b0A0 ph5:b0B0 ph6:b0B1 ph7:b0A1 ph8:b1A0
// vmcnt(4) at end of EVERY phase retires stages <= ph(p-2).
// XOR-swizzle (row&7)<<4 via pre-swizzled global source + swizzled ds_read.
// LDS byte regions: buf0: A0=0 A1=16384 B0=32768 B1=49152; buf1: +65536.
#define RD_A(DST, OFF) { _Pragma("unroll") for (int m_ = 0; m_ < 4; ++m_) { \
    _Pragma("unroll") for (int kk_ = 0; kk_ < 2; ++kk_) { \
        DST[m_][kk_] = *(const bf16x8*)(ldsc + (OFF) + rA[m_] + kb[kk_]); } } }
#define RD_B(DST, OFF) { _Pragma("unroll") for (int n_ = 0; n_ < 2; ++n_) { \
    _Pragma("unroll") for (int kk_ = 0; kk_ < 2; ++kk_) { \
        DST[n_][kk_] = *(const bf16x8*)(ldsc + (OFF) + rB[n_] + kb[kk_]); } } }
#define MMQ(MH, NH, AB, BB) { _Pragma("unroll") for (int m_ = 0; m_ < 4; ++m_) { \
    _Pragma("unroll") for (int n_ = 0; n_ < 2; ++n_) { \
    _Pragma("unroll") for (int kk_ = 0; kk_ < 2; ++kk_) { \
        acc[MH][NH][m_][n_] = __builtin_amdgcn_mfma_f32_16x16x32_bf16( \
            AB[m_][kk_], BB[n_][kk_], acc[MH][NH][m_][n_], 0, 0, 0); } } } }
#define BAR() __builtin_amdgcn_s_barrier()
#define PRIO1() __builtin_amdgcn_s_setprio(1)
#define PRIO0() __builtin_amdgcn_s_setprio(0)
#define VMCNT4() asm volatile("s_waitcnt vmcnt(4)" ::: "memory")
#define VMCNT2() asm volatile("s_waitcnt vmcnt(2)" ::: "memory")

__global__ __launch_bounds__(512, 2)
void gemm_dist(const unsigned short* __restrict__ Abf, const float* __restrict__ sq,
               float* __restrict__ D) {
    __shared__ unsigned short lds[65536];   // 128 KB
    const char* ldsc = (const char*)lds;
    const int tid = threadIdx.x;
    const int wid = tid >> 6, lane = tid & 63;
    const int wr = wid >> 2, wc = wid & 3;
    const int fr = lane & 15;
    const int key = (fr & 7) << 4;
    const int klin = (lane >> 4) << 4;     // byte offset of 16B k-slot
    int kb[2];
    kb[0] = klin ^ key;
    kb[1] = (64 | klin) ^ key;
    int rA[4], rB[2];
#pragma unroll
    for (int m = 0; m < 4; ++m) rA[m] = (wr * 64 + m * 16 + fr) * 128;
#pragma unroll
    for (int n = 0; n < 2; ++n) rB[n] = (wc * 32 + n * 16 + fr) * 128;

    const int swz = (blockIdx.x & 7) * 32 + (blockIdx.x >> 3);  // XCD-chunked
    const int bi = swz >> 4, bj = swz & 15;
    const int rowC0 = bi * 256, colC0 = bj * 256;

    // per-thread staging source (inverse-swizzled k: linear LDS + swz read = identity)
    const int srow = tid >> 3;
    const int ksrc = ((tid & 7) ^ (srow & 7)) << 3;
    const unsigned short* aSt = Abf + (size_t)(rowC0 + srow) * K_DIM + ksrc;
    const unsigned short* bSt = Abf + (size_t)(colC0 + srow) * K_DIM + ksrc;
    // wave-uniform LDS stage bases (ushort offsets)
    unsigned short* Lb0A0 = lds + 0     + wid * 512;
    unsigned short* Lb0A1 = lds + 8192  + wid * 512;
    unsigned short* Lb0B0 = lds + 16384 + wid * 512;
    unsigned short* Lb0B1 = lds + 24576 + wid * 512;
    unsigned short* Lb1A0 = lds + 32768 + wid * 512;
    unsigned short* Lb1A1 = lds + 40960 + wid * 512;
    unsigned short* Lb1B0 = lds + 49152 + wid * 512;
    unsigned short* Lb1B1 = lds + 57344 + wid * 512;

    floatx4 acc[2][2][4][2];
#pragma unroll
    for (int a0 = 0; a0 < 2; ++a0)
#pragma unroll
    for (int a1 = 0; a1 < 2; ++a1)
#pragma unroll
    for (int a2 = 0; a2 < 4; ++a2)
#pragma unroll
    for (int a3 = 0; a3 < 2; ++a3) acc[a0][a1][a2][a3] = (floatx4){0.f, 0.f, 0.f, 0.f};
    bf16x8 afX[4][2], afY[4][2], bfP[2][2], bfQ[2][2];

    // prologue: stage tile0 {A0,B0,B1,A1} + tile1.A0; read tile0 A0,B0 to regs
    stage_half(aSt,          Lb0A0);
    stage_half(bSt,          Lb0B0);
    stage_half(bSt + 262144, Lb0B1);
    stage_half(aSt + 262144, Lb0A1);
    stage_half(aSt + 64,     Lb1A0);
    VMCNT2();            // tile0 all landed (b1A0's 2 may be outstanding)
    BAR();
    RD_A(afY, 0); RD_B(bfP, 32768);

    for (int it = 0; it < NIT; ++it) {
        const int t64 = it * 128;           // k-elem base of tile a=2*it
        const bool pf = (it < NIT - 1);
        // ph1: MMQ(0,0)<-afY,bfP | read B1->bfQ (for ph2,3) | stage b1B0
        RD_B(bfQ, 49152);
        stage_half(bSt + t64 + 64, Lb1B0);
        PRIO1(); MMQ(0, 0, afY, bfP); PRIO0(); VMCNT4(); BAR();
        // ph2: MMQ(0,1)<-afY,bfQ | read A1->afX (ph3,4) | stage b1B1
        RD_A(afX, 16384);
        stage_half(bSt + 262144 + t64 + 64, Lb1B1);
        PRIO1(); MMQ(0, 1, afY, bfQ); PRIO0(); VMCNT4(); BAR();
        // ph3: MMQ(1,1)<-afX,bfQ | read B0->bfP (ph4) | stage b1A1
        RD_B(bfP, 32768);
        stage_half(aSt + 262144 + t64 + 64, Lb1A1);
        PRIO1(); MMQ(1, 1, afX, bfQ); PRIO0(); VMCNT4(); BAR();
        // ph4: MMQ(1,0)<-afX,bfP | read A0',B0'->afY,bfQ (ph5,6) | stage b0A0(a+2)
        RD_A(afY, 65536); RD_B(bfQ, 98304);
        if (pf) stage_half(aSt + t64 + 128, Lb0A0);
        PRIO1(); MMQ(1, 0, afX, bfP); PRIO0(); VMCNT4(); BAR();
        // ph5: MMQ(0,0)<-afY,bfQ | read B1'->bfP (ph6,7) | stage b0B0(a+2)
        RD_B(bfP, 114688);
        if (pf) stage_half(bSt + t64 + 128, Lb0B0);
        PRIO1(); MMQ(0, 0, afY, bfQ); PRIO0(); VMCNT4(); BAR();
        // ph6: MMQ(0,1)<-afY,bfP | read A1'->afX (ph7,8) | stage b0B1(a+2)
        RD_A(afX, 81920);
        if (pf) stage_half(bSt + 262144 + t64 + 128, Lb0B1);
        PRIO1(); MMQ(0, 1, afY, bfP); PRIO0(); VMCNT4(); BAR();
        // ph7: MMQ(1,1)<-afX,bfP | read B0'->bfQ (ph8) | stage b0A1(a+2)
        RD_B(bfQ, 98304);
        if (pf) stage_half(aSt + 262144 + t64 + 128, Lb0A1);
        PRIO1(); MMQ(1, 1, afX, bfP); PRIO0(); VMCNT4(); BAR();
        // ph8: MMQ(1,0)<-afX,bfQ | read A0,B0 (a+2) -> afY,bfP | stage b1A0(a+3)
        if (pf) { RD_A(afY, 0); RD_B(bfP, 32768); }
        if (pf) stage_half(aSt + t64 + 192, Lb1A0);
        PRIO1(); MMQ(1, 0, afX, bfQ); PRIO0(); VMCNT4(); BAR();
    }

    // epilogue: D[i][j] = sqrt(max(sq_i + sq_j - 2*dot, 1e-12))
#pragma unroll
    for (int MH = 0; MH < 2; ++MH)
#pragma unroll
    for (int NH = 0; NH < 2; ++NH)
#pragma unroll
    for (int m = 0; m < 4; ++m)
#pragma unroll
    for (int n = 0; n < 2; ++n) {
        const int col = colC0 + NH * 128 + wc * 32 + n * 16 + fr;
        const int row0 = rowC0 + MH * 128 + wr * 64 + m * 16 + (lane >> 4) * 4;
        const float sqc = sq[col];
#pragma unroll
        for (int r = 0; r < 4; ++r) {
            float d2 = sq[row0 + r] + sqc - 2.0f * acc[MH][NH][m][n][r];
            D[(size_t)(row0 + r) * N_DIM + col] = sqrtf(fmaxf(d2, 1e-12f));
        }
    }
}

// ---------------- Kernel 2: per-row hardest-pos / hardest-neg --------------
__global__ __launch_bounds__(256)
void rowstats(const float* __restrict__ D, const int* __restrict__ tgt,
              float* __restrict__ ap, float* __restrict__ an,
              int* __restrict__ pOut, int* __restrict__ qOut) {
    const int i = blockIdx.x, tid = threadIdx.x;
    const int ti = tgt[i];
    const float* row = D + (size_t)i * N_DIM;
    float bmax = -INFINITY; int bp = -1;
    float bmin = INFINITY;  int bq = -1;
#pragma unroll
    for (int it = 0; it < 4; ++it) {
        const int j0 = (it * 256 + tid) * 4;
        floatx4 d = *(const floatx4*)(row + j0);
        intx4 t4 = *(const intx4*)(tgt + j0);
#pragma unroll
        for (int e = 0; e < 4; ++e) {
            const int j = j0 + e; const float dv = d[e];
            if (t4[e] == ti) {
                if (dv > bmax || (dv == bmax && j > bp)) { bmax = dv; bp = j; }
            } else {
                if (dv < bmin || (dv == bmin && j > bq)) { bmin = dv; bq = j; }
            }
        }
    }
    __shared__ float smax[256]; __shared__ int sip[256];
    __shared__ float smin[256]; __shared__ int siq[256];
    smax[tid] = bmax; sip[tid] = bp; smin[tid] = bmin; siq[tid] = bq;
    __syncthreads();
    for (int off = 128; off; off >>= 1) {
        if (tid < off) {
            float v = smax[tid + off]; int ix = sip[tid + off];
            if (v > smax[tid] || (v == smax[tid] && ix > sip[tid])) { smax[tid] = v; sip[tid] = ix; }
            float w = smin[tid + off]; int iy = siq[tid + off];
            if (w < smin[tid] || (w == smin[tid] && iy > siq[tid])) { smin[tid] = w; siq[tid] = iy; }
        }
        __syncthreads();
    }
    if (tid == 0) { ap[i] = smax[0]; pOut[i] = sip[0]; an[i] = smin[0]; qOut[i] = siq[0]; }
}

// ---------------- Kernel 3: third-class scan on row q[i], per-row loss -----
__global__ __launch_bounds__(256)
void pass2(const float* __restrict__ D, const int* __restrict__ tgt,
           const float* __restrict__ ap, const float* __restrict__ an,
           const int* __restrict__ pArr, const int* __restrict__ qArr,
           float* __restrict__ lossArr) {
    const int i = blockIdx.x, tid = threadIdx.x;
    const int q = qArr[i];
    const int ti = tgt[i], lq = tgt[q];
    const float* rowq = D + (size_t)q * N_DIM;
    float bmin = INFINITY; int br = -1;
#pragma unroll
    for (int it = 0; it < 4; ++it) {
        const int j0 = (it * 256 + tid) * 4;
        floatx4 d = *(const floatx4*)(rowq + j0);
        intx4 t4 = *(const intx4*)(tgt + j0);
#pragma unroll
        for (int e = 0; e < 4; ++e) {
            const int j = j0 + e; const float dv = d[e];
            if (t4[e] != ti && t4[e] != lq) {
                if (dv < bmin || (dv == bmin && j > br)) { bmin = dv; br = j; }
            }
        }
    }
    __shared__ float sm[256]; __shared__ int si[256];
    sm[tid] = bmin; si[tid] = br;
    __syncthreads();
    for (int off = 128; off; off >>= 1) {
        if (tid < off) {
            float v = sm[tid + off]; int ix = si[tid + off];
            if (v < sm[tid] || (v == sm[tid] && ix > si[tid])) { sm[tid] = v; si[tid] = ix; }
        }
        __syncthreads();
    }
    if (tid == 0) {
        const int r = si[0]; const float okmin = sm[0];
        const float an2 = D[(size_t)pArr[i] * N_DIM + q];
        const float an3 = D[(size_t)i * N_DIM + r];
        lossArr[i] = fmaxf(ap[i] - an[i], 0.f) + fabsf(an[i] - an2) + fabsf(an3 - okmin);
    }
}

// ---------------- Kernel 4: final sum / n -----------------------------------
__global__ __launch_bounds__(256)
void finred(const float* __restrict__ lossArr, float* __restrict__ out) {
    const int tid = threadIdx.x;
    float s = 0.f;
    for (int j = tid; j < N_DIM; j += 256) s += lossArr[j];
#pragma unroll
    for (int off = 32; off; off >>= 1) s += __shfl_down(s, off);
    __shared__ float w[4];
    const int wave = tid >> 6, lane = tid & 63;
    if (lane == 0) w[wave] = s;
    __syncthreads();
    if (tid == 0) out[0] = (w[0] + w[1] + w[2] + w[3]) * (1.0f / (float)N_DIM);
}

extern "C" void kernel_launch(void* const* d_in, const int* in_sizes, int n_in,
                              void* d_out, int out_size, void* d_ws, size_t ws_size,
                              hipStream_t stream) {
    const float* X = (const float*)d_in[0];
    const int* tgt = (const int*)d_in[1];
    float* out = (float*)d_out;

    char* w = (char*)d_ws;
    unsigned short* Abf = (unsigned short*)w;                 // 16 MB
    float* D = (float*)(w + ((size_t)16 << 20));              // 64 MB
    float* sq = (float*)(w + ((size_t)80 << 20));             // 16 KB
    float* ap = sq + N_DIM;
    float* an = ap + N_DIM;
    float* lossArr = an + N_DIM;
    int* pA = (int*)(lossArr + N_DIM);
    int* qA = pA + N_DIM;

    prep_kernel<<<N_DIM, 256, 0, stream>>>(X, Abf, sq);
    gemm_dist<<<256, 512, 0, stream>>>(Abf, sq, D);
    rowstats<<<N_DIM, 256, 0, stream>>>(D, tgt, ap, an, pA, qA);
    pass2<<<N_DIM, 256, 0, stream>>>(D, tgt, ap, an, pA, qA, lossArr);
    finred<<<1, 256, 0, stream>>>(lossArr, out);
}

// Round 6
// 106.159 us; speedup vs baseline: 1.2818x; 1.2818x over previous
//
#include <hip/hip_runtime.h>
#include <hip/hip_bf16.h>
#include <cstdint>

#define N_DIM 4096
#define K_DIM 2048
#define NIT 16   // 32 K-tiles of 64, 2 per iteration

typedef __bf16 bf16x8 __attribute__((ext_vector_type(8)));
typedef float floatx4 __attribute__((ext_vector_type(4)));
typedef unsigned short ushort8 __attribute__((ext_vector_type(8)));
typedef int intx4 __attribute__((ext_vector_type(4)));

__device__ __forceinline__ unsigned short f2bf(float f) {
    unsigned int u = __builtin_bit_cast(unsigned int, f);
    unsigned int r = (u + 0x7fffu + ((u >> 16) & 1u)) >> 16;  // RNE
    return (unsigned short)r;
}

__device__ __forceinline__ void gld_lds16(const void* g, void* l) {
    __builtin_amdgcn_global_load_lds(
        (const __attribute__((address_space(1))) unsigned int*)g,
        (__attribute__((address_space(3))) unsigned int*)l,
        16, 0, 0);
}

__device__ __forceinline__ void stage_half(const unsigned short* src, unsigned short* ldsWave) {
    gld_lds16(src, ldsWave);                       // rows 0-63 of the half
    gld_lds16(src + 64 * K_DIM, ldsWave + 4096);   // rows 64-127 (+8192 B)
}

// ---------------- Kernel 0: cast fp32 -> bf16, compute row squared norms ----
__global__ __launch_bounds__(256)
void prep_kernel(const float* __restrict__ X, unsigned short* __restrict__ Abf,
                 float* __restrict__ sq) {
    const int row = blockIdx.x;
    const int tid = threadIdx.x;
    const float* xr = X + (size_t)row * K_DIM;
    floatx4 a = *(const floatx4*)(xr + tid * 8);
    floatx4 b = *(const floatx4*)(xr + tid * 8 + 4);
    float s = 0.f;
    ushort8 o;
#pragma unroll
    for (int e = 0; e < 4; ++e) {
        s += a[e] * a[e] + b[e] * b[e];
        o[e] = f2bf(a[e]);
        o[4 + e] = f2bf(b[e]);
    }
    *(ushort8*)(Abf + (size_t)row * K_DIM + tid * 8) = o;
#pragma unroll
    for (int off = 32; off; off >>= 1) s += __shfl_down(s, off);
    __shared__ float wsum[4];
    const int wave = tid >> 6, lane = tid & 63;
    if (lane == 0) wsum[wave] = s;
    __syncthreads();
    if (tid == 0) sq[row] = wsum[0] + wsum[1] + wsum[2] + wsum[3];
}

// ---------------- Kernel 1: 256x256 8-phase bf16 MFMA GEMM + dist epilogue --
// 512 thr = 8 waves (2Mx4N). BK=64, 2 K-tiles/iter. Phase = {ds_reads for
// THIS phase's MFMA | stage | [vmcnt] | BARRIER | MFMA}. Barrier sits
// between reads and MFMA (m201 placement): phase p+1's reads are issued
// right after MFMA_p issue, so LDS serves them while MFMA_p drains.
// Zero extra frag registers (round-5's reg pipeline spilled; this doesn't).
// Quadrants (0,0),(0,1),(1,1),(1,0); A-frag held 2 phases; B0 re-read.
// Stage slots (WAR gap >= 2 phases from region's last read):
//   ph1:b1A1<-(a+1) ph2:b1B0<-(a+1) ph3:b0A0<-(a+2) ph4:b0B1<-(a+2)
//   ph5:b0A1<-(a+2) ph6:b0B0<-(a+2) ph7:b1A0<-(a+3) ph8:b1B1<-(a+3)
// vmcnt(4) before bar_4 and bar_8 only (counted, FIFO-verified; 0 on last).
// XOR-swizzle (row&7)<<4 via pre-swizzled global source + swizzled ds_read.
// LDS byte regions: buf0: A0=0 A1=16384 B0=32768 B1=49152; buf1: +65536.
#define RD_A(OFF) { _Pragma("unroll") for (int m_ = 0; m_ < 4; ++m_) { \
    _Pragma("unroll") for (int kk_ = 0; kk_ < 2; ++kk_) { \
        af[m_][kk_] = *(const bf16x8*)(ldsc + (OFF) + rA[m_] + kb[kk_]); } } }
#define RD_B(OFF) { _Pragma("unroll") for (int n_ = 0; n_ < 2; ++n_) { \
    _Pragma("unroll") for (int kk_ = 0; kk_ < 2; ++kk_) { \
        bfv[n_][kk_] = *(const bf16x8*)(ldsc + (OFF) + rB[n_] + kb[kk_]); } } }
#define MMQ(MH, NH) { _Pragma("unroll") for (int m_ = 0; m_ < 4; ++m_) { \
    _Pragma("unroll") for (int n_ = 0; n_ < 2; ++n_) { \
    _Pragma("unroll") for (int kk_ = 0; kk_ < 2; ++kk_) { \
        acc[MH][NH][m_][n_] = __builtin_amdgcn_mfma_f32_16x16x32_bf16( \
            af[m_][kk_], bfv[n_][kk_], acc[MH][NH][m_][n_], 0, 0, 0); } } } }
#define BAR() __builtin_amdgcn_s_barrier()
#define PRIO1() __builtin_amdgcn_s_setprio(1)
#define PRIO0() __builtin_amdgcn_s_setprio(0)
#define VMCNT4() asm volatile("s_waitcnt vmcnt(4)" ::: "memory")
#define VMCNT0() asm volatile("s_waitcnt vmcnt(0)" ::: "memory")

__global__ __launch_bounds__(512, 2)
void gemm_dist(const unsigned short* __restrict__ Abf, const float* __restrict__ sq,
               float* __restrict__ D) {
    __shared__ unsigned short lds[65536];   // 128 KB
    const char* ldsc = (const char*)lds;
    const int tid = threadIdx.x;
    const int wid = tid >> 6, lane = tid & 63;
    const int wr = wid >> 2, wc = wid & 3;
    const int fr = lane & 15;
    const int key = (fr & 7) << 4;
    const int klin = (lane >> 4) << 4;     // byte offset of 16B k-slot
    int kb[2];
    kb[0] = klin ^ key;
    kb[1] = (64 | klin) ^ key;
    int rA[4], rB[2];
#pragma unroll
    for (int m = 0; m < 4; ++m) rA[m] = (wr * 64 + m * 16 + fr) * 128;
#pragma unroll
    for (int n = 0; n < 2; ++n) rB[n] = (wc * 32 + n * 16 + fr) * 128;

    const int swz = (blockIdx.x & 7) * 32 + (blockIdx.x >> 3);  // XCD-chunked
    const int bi = swz >> 4, bj = swz & 15;
    const int rowC0 = bi * 256, colC0 = bj * 256;

    // per-thread staging source (inverse-swizzled k: linear LDS + swz read = identity)
    const int srow = tid >> 3;
    const int ksrc = ((tid & 7) ^ (srow & 7)) << 3;
    const unsigned short* aSt = Abf + (size_t)(rowC0 + srow) * K_DIM + ksrc;
    const unsigned short* bSt = Abf + (size_t)(colC0 + srow) * K_DIM + ksrc;
    // wave-uniform LDS stage bases (ushort offsets)
    unsigned short* Lb0A0 = lds + 0     + wid * 512;
    unsigned short* Lb0A1 = lds + 8192  + wid * 512;
    unsigned short* Lb0B0 = lds + 16384 + wid * 512;
    unsigned short* Lb0B1 = lds + 24576 + wid * 512;
    unsigned short* Lb1A0 = lds + 32768 + wid * 512;
    unsigned short* Lb1A1 = lds + 40960 + wid * 512;
    unsigned short* Lb1B0 = lds + 49152 + wid * 512;
    unsigned short* Lb1B1 = lds + 57344 + wid * 512;

    floatx4 acc[2][2][4][2];
#pragma unroll
    for (int a0 = 0; a0 < 2; ++a0)
#pragma unroll
    for (int a1 = 0; a1 < 2; ++a1)
#pragma unroll
    for (int a2 = 0; a2 < 4; ++a2)
#pragma unroll
    for (int a3 = 0; a3 < 2; ++a3) acc[a0][a1][a2][a3] = (floatx4){0.f, 0.f, 0.f, 0.f};
    bf16x8 af[4][2], bfv[2][2];

    // prologue: t0 {A0,B0,B1,A1} + t1 {A0,B1}; vmcnt(4) = t0 fully landed
    stage_half(aSt,               Lb0A0);
    stage_half(bSt,               Lb0B0);
    stage_half(bSt + 262144,      Lb0B1);
    stage_half(aSt + 262144,      Lb0A1);
    stage_half(aSt + 64,          Lb1A0);
    stage_half(bSt + 262144 + 64, Lb1B1);
    VMCNT4();
    BAR();

    for (int it = 0; it < NIT; ++it) {
        const int t64 = it * 128;           // k-elem base of tile a=2*it
        const bool pf = (it < NIT - 1);
        // ph1: reads A0,B0 | stage (a+1).A1 -> b1A1 | BAR | MMQ(0,0)
        RD_A(0); RD_B(32768);
        stage_half(aSt + 262144 + t64 + 64, Lb1A1);
        BAR(); PRIO1(); MMQ(0, 0); PRIO0();
        // ph2: reads B1 | stage (a+1).B0 -> b1B0 | BAR | MMQ(0,1)
        RD_B(49152);
        stage_half(bSt + t64 + 64, Lb1B0);
        BAR(); PRIO1(); MMQ(0, 1); PRIO0();
        // ph3: reads A1 | stage (a+2).A0 -> b0A0 | BAR | MMQ(1,1)
        RD_A(16384);
        if (pf) stage_half(aSt + t64 + 128, Lb0A0);
        BAR(); PRIO1(); MMQ(1, 1); PRIO0();
        // ph4: reads B0 | stage (a+2).B1 -> b0B1 | vmcnt | BAR | MMQ(1,0)
        RD_B(32768);
        if (pf) stage_half(bSt + 262144 + t64 + 128, Lb0B1);
        if (pf) { VMCNT4(); } else { VMCNT0(); }
        BAR(); PRIO1(); MMQ(1, 0); PRIO0();
        // ph5: reads A0',B0' | stage (a+2).A1 -> b0A1 | BAR | MMQ(0,0)
        RD_A(65536); RD_B(98304);
        if (pf) stage_half(aSt + 262144 + t64 + 128, Lb0A1);
        BAR(); PRIO1(); MMQ(0, 0); PRIO0();
        // ph6: reads B1' | stage (a+2).B0 -> b0B0 | BAR | MMQ(0,1)
        RD_B(114688);
        if (pf) stage_half(bSt + t64 + 128, Lb0B0);
        BAR(); PRIO1(); MMQ(0, 1); PRIO0();
        // ph7: reads A1' | stage (a+3).A0 -> b1A0 | BAR | MMQ(1,1)
        RD_A(81920);
        if (pf) stage_half(aSt + t64 + 192, Lb1A0);
        BAR(); PRIO1(); MMQ(1, 1); PRIO0();
        // ph8: reads B0' | stage (a+3).B1 -> b1B1 | vmcnt | BAR | MMQ(1,0)
        RD_B(98304);
        if (pf) stage_half(bSt + 262144 + t64 + 192, Lb1B1);
        if (pf) { VMCNT4(); } else { VMCNT0(); }
        BAR(); PRIO1(); MMQ(1, 0); PRIO0();
    }

    // epilogue: D[i][j] = sqrt(max(sq_i + sq_j - 2*dot, 1e-12))
#pragma unroll
    for (int MH = 0; MH < 2; ++MH)
#pragma unroll
    for (int NH = 0; NH < 2; ++NH)
#pragma unroll
    for (int m = 0; m < 4; ++m)
#pragma unroll
    for (int n = 0; n < 2; ++n) {
        const int col = colC0 + NH * 128 + wc * 32 + n * 16 + fr;
        const int row0 = rowC0 + MH * 128 + wr * 64 + m * 16 + (lane >> 4) * 4;
        const float sqc = sq[col];
#pragma unroll
        for (int r = 0; r < 4; ++r) {
            float d2 = sq[row0 + r] + sqc - 2.0f * acc[MH][NH][m][n][r];
            D[(size_t)(row0 + r) * N_DIM + col] = sqrtf(fmaxf(d2, 1e-12f));
        }
    }
}

// ---------------- Kernel 2: per-row hardest-pos / hardest-neg --------------
__global__ __launch_bounds__(256)
void rowstats(const float* __restrict__ D, const int* __restrict__ tgt,
              float* __restrict__ ap, float* __restrict__ an,
              int* __restrict__ pOut, int* __restrict__ qOut) {
    const int i = blockIdx.x, tid = threadIdx.x;
    const int ti = tgt[i];
    const float* row = D + (size_t)i * N_DIM;
    float bmax = -INFINITY; int bp = -1;
    float bmin = INFINITY;  int bq = -1;
#pragma unroll
    for (int it = 0; it < 4; ++it) {
        const int j0 = (it * 256 + tid) * 4;
        floatx4 d = *(const floatx4*)(row + j0);
        intx4 t4 = *(const intx4*)(tgt + j0);
#pragma unroll
        for (int e = 0; e < 4; ++e) {
            const int j = j0 + e; const float dv = d[e];
            if (t4[e] == ti) {
                if (dv > bmax || (dv == bmax && j > bp)) { bmax = dv; bp = j; }
            } else {
                if (dv < bmin || (dv == bmin && j > bq)) { bmin = dv; bq = j; }
            }
        }
    }
    __shared__ float smax[256]; __shared__ int sip[256];
    __shared__ float smin[256]; __shared__ int siq[256];
    smax[tid] = bmax; sip[tid] = bp; smin[tid] = bmin; siq[tid] = bq;
    __syncthreads();
    for (int off = 128; off; off >>= 1) {
        if (tid < off) {
            float v = smax[tid + off]; int ix = sip[tid + off];
            if (v > smax[tid] || (v == smax[tid] && ix > sip[tid])) { smax[tid] = v; sip[tid] = ix; }
            float w = smin[tid + off]; int iy = siq[tid + off];
            if (w < smin[tid] || (w == smin[tid] && iy > siq[tid])) { smin[tid] = w; siq[tid] = iy; }
        }
        __syncthreads();
    }
    if (tid == 0) { ap[i] = smax[0]; pOut[i] = sip[0]; an[i] = smin[0]; qOut[i] = siq[0]; }
}

// ---------------- Kernel 3: third-class scan on row q[i], per-row loss -----
__global__ __launch_bounds__(256)
void pass2(const float* __restrict__ D, const int* __restrict__ tgt,
           const float* __restrict__ ap, const float* __restrict__ an,
           const int* __restrict__ pArr, const int* __restrict__ qArr,
           float* __restrict__ lossArr) {
    const int i = blockIdx.x, tid = threadIdx.x;
    const int q = qArr[i];
    const int ti = tgt[i], lq = tgt[q];
    const float* rowq = D + (size_t)q * N_DIM;
    float bmin = INFINITY; int br = -1;
#pragma unroll
    for (int it = 0; it < 4; ++it) {
        const int j0 = (it * 256 + tid) * 4;
        floatx4 d = *(const floatx4*)(rowq + j0);
        intx4 t4 = *(const intx4*)(tgt + j0);
#pragma unroll
        for (int e = 0; e < 4; ++e) {
            const int j = j0 + e; const float dv = d[e];
            if (t4[e] != ti && t4[e] != lq) {
                if (dv < bmin || (dv == bmin && j > br)) { bmin = dv; br = j; }
            }
        }
    }
    __shared__ float sm[256]; __shared__ int si[256];
    sm[tid] = bmin; si[tid] = br;
    __syncthreads();
    for (int off = 128; off; off >>= 1) {
        if (tid < off) {
            float v = sm[tid + off]; int ix = si[tid + off];
            if (v < sm[tid] || (v == sm[tid] && ix > si[tid])) { sm[tid] = v; si[tid] = ix; }
        }
        __syncthreads();
    }
    if (tid == 0) {
        const int r = si[0]; const float okmin = sm[0];
        const float an2 = D[(size_t)pArr[i] * N_DIM + q];
        const float an3 = D[(size_t)i * N_DIM + r];
        lossArr[i] = fmaxf(ap[i] - an[i], 0.f) + fabsf(an[i] - an2) + fabsf(an3 - okmin);
    }
}

// ---------------- Kernel 4: final sum / n -----------------------------------
__global__ __launch_bounds__(256)
void finred(const float* __restrict__ lossArr, float* __restrict__ out) {
    const int tid = threadIdx.x;
    float s = 0.f;
    for (int j = tid; j < N_DIM; j += 256) s += lossArr[j];
#pragma unroll
    for (int off = 32; off; off >>= 1) s += __shfl_down(s, off);
    __shared__ float w[4];
    const int wave = tid >> 6, lane = tid & 63;
    if (lane == 0) w[wave] = s;
    __syncthreads();
    if (tid == 0) out[0] = (w[0] + w[1] + w[2] + w[3]) * (1.0f / (float)N_DIM);
}

extern "C" void kernel_launch(void* const* d_in, const int* in_sizes, int n_in,
                              void* d_out, int out_size, void* d_ws, size_t ws_size,
                              hipStream_t stream) {
    const float* X = (const float*)d_in[0];
    const int* tgt = (const int*)d_in[1];
    float* out = (float*)d_out;

    char* w = (char*)d_ws;
    unsigned short* Abf = (unsigned short*)w;                 // 16 MB
    float* D = (float*)(w + ((size_t)16 << 20));              // 64 MB
    float* sq = (float*)(w + ((size_t)80 << 20));             // 16 KB
    float* ap = sq + N_DIM;
    float* an = ap + N_DIM;
    float* lossArr = an + N_DIM;
    int* pA = (int*)(lossArr + N_DIM);
    int* qA = pA + N_DIM;

    prep_kernel<<<N_DIM, 256, 0, stream>>>(X, Abf, sq);
    gemm_dist<<<256, 512, 0, stream>>>(Abf, sq, D);
    rowstats<<<N_DIM, 256, 0, stream>>>(D, tgt, ap, an, pA, qA);
    pass2<<<N_DIM, 256, 0, stream>>>(D, tgt, ap, an, pA, qA, lossArr);
    finred<<<1, 256, 0, stream>>>(lossArr, out);
}